// Round 4
// baseline (258.058 us; speedup 1.0000x reference)
//
#include <hip/hip_runtime.h>

// Bilinear warp (grid_sample, zeros padding) of frame_t (8,64,256,256) fp32
// by flow_field (8,2,256,256) fp32.
//   ix = px + 0.5*flow_x ; iy = py + 0.5*flow_y   (normalization collapses)
//
// R7 — R6 retry. R6 (global_load_lds staging) FAILED correctness (absmax
// 5.7); the weight math re-verified case-by-case, so the suspect is the
// async-staging path (addrspace cast / lane layout). R7 keeps the R6
// weight-amortization structure but reverts staging to the R5-PROVEN
// float4-load + LDS-store path (identical indexing to the passing R5).
//
//  - Block = (b, band, cgroup of 8 channels); grid 8*16*8 = 1024 = exactly
//    4 blocks/CU (40 KiB window x 4 = 160 KiB LDS). Weights computed ONCE
//    per block into register arrays (w00..w11, oidx, badmask), reused for
//    8 channels -> ~35 VALU/pixel of flow->weight pipeline amortized 8x.
//  - Edge-remap: border validity + clamp folded into the 4 weights
//    (ea/eb per x: ix0==-1 / ix0==255 move the valid tap's weight onto the
//    in-window sample; y clamp via staging row replication + ey zeroing).
//    Inner loop = 4 ds_read + 4 FMA + 1 store. Zero edge logic.
//  - Window misses (|disp|>~12, ~0.05%/px) -> badmask, fixed up after the
//    gather per channel with global taps (flow reloaded from L2).
//  - Two barriers per channel transition: reads done -> overwrite window;
//    writes done -> next gather.
//  - b in low 3 bits of blockIdx -> XCD-local; band fastest -> 28/40-row
//    L2 overlap between adjacent blocks.

#define B_ 8
#define C_ 64
#define H_ 256
#define W_ 256
#define HW_ (H_ * W_)
#define BAND 16
#define NBAND (H_ / BAND)
#define HALO 12
#define WROWS (BAND + 2 * HALO)        // 40 rows
#define WFLOATS (WROWS * W_)           // 10240 floats = 40 KiB
#define WMAXBR (WROWS - 2)             // 38: max base row (reads brw, brw+1)
#define CG 8                           // channels per block

__global__ __launch_bounds__(256, 4) void warp_bilinear_kernel(
    const float* __restrict__ frame,   // (8,64,256,256)
    const float* __restrict__ flow,    // (8,2,256,256)
    float* __restrict__ out)           // (8,64,256,256)
{
    __shared__ float win[WFLOATS];

    const int blk  = blockIdx.x;
    const int b    = blk & 7;          // XCD-local batch
    const int t    = blk >> 3;
    const int band = t & (NBAND - 1);  // fastest: adjacent blocks overlap rows
    const int cg   = t >> 4;           // 0..7
    const int c0   = cg * CG;

    const int r0  = band * BAND;
    const int wlo = r0 - HALO;         // first window row (may be <0)

    const int tid = threadIdx.x;       // 0..255 == pixel column
    const int px  = tid;

    const size_t bc0 = (size_t)(b * C_ + c0) * HW_;

    // ---- stage one 40x256 window (R5-proven float4 path) ----
    auto stage = [&](int ch) {
        const float* __restrict__ s = frame + bc0 + (size_t)ch * HW_;
#pragma unroll
        for (int it = 0; it < WFLOATS / (256 * 4); ++it) {   // 10 iters
            const int lin = it * 1024 + tid * 4;             // float idx in window
            const int wr  = lin >> 8;                        // window row
            const int wx  = lin & 255;
            const int gy  = min(max(wlo + wr, 0), H_ - 1);   // clamp = y replication
            *(float4*)(win + lin) = *(const float4*)(s + gy * W_ + wx);
        }
    };

    stage(0);

    // ---- flow for this band ----
    const int spbase = r0 * W_ + px;
    const float* __restrict__ flx = flow + (size_t)(b * 2 + 0) * HW_;
    const float* __restrict__ fly = flow + (size_t)(b * 2 + 1) * HW_;

    float fx[BAND], fy[BAND];
#pragma unroll
    for (int r = 0; r < BAND; ++r) {
        fx[r] = flx[spbase + r * W_];
        fy[r] = fly[spbase + r * W_];
    }

    // ---- weights + addresses, ONCE for all CG channels ----
    float w00[BAND], w01[BAND], w10[BAND], w11[BAND];
    int   oidx[BAND];
    unsigned badmask = 0u;

#pragma unroll
    for (int r = 0; r < BAND; ++r) {
        const int py = r0 + r;
        const float ix = (float)px + 0.5f * fx[r];
        const float iy = (float)py + 0.5f * fy[r];

        const float ix0f = floorf(ix);
        const float iy0f = floorf(iy);
        const float wx1 = ix - ix0f;
        const float wx0 = 1.0f - wx1;
        const float wy1 = iy - iy0f;
        const float wy0 = 1.0f - wy1;

        const int ix0 = (int)ix0f;
        const int iy0 = (int)iy0f;

        // x edge-remap onto base=clamp(ix0,0,254): a=col base, b=col base+1
        //  ix0 in [0,254]: ea=wx0, eb=wx1
        //  ix0 == -1    : x1 tap (col 0) lands on a -> ea=wx1, eb=0
        //  ix0 == 255   : x0 tap (col 255) lands on b -> ea=0, eb=wx0
        //  else         : both taps invalid -> 0, 0
        float ea = wx0, eb = wx1;
        if (ix0 == -1)                { ea = wx1;  eb = 0.0f; }
        if (ix0 == W_ - 1)            { ea = 0.0f; eb = wx0;  }
        if (ix0 < -1 || ix0 > W_ - 1) { ea = 0.0f; eb = 0.0f; }

        // y validity (zeros padding); y clamp comes from staging replication
        const float ey0 = ((unsigned)iy0       < (unsigned)H_) ? wy0 : 0.0f;
        const float ey1 = ((unsigned)(iy0 + 1) < (unsigned)H_) ? wy1 : 0.0f;

        w00[r] = ey0 * ea; w01[r] = ey0 * eb;
        w10[r] = ey1 * ea; w11[r] = ey1 * eb;

        const int base = min(max(ix0, 0), W_ - 2);   // 0..254
        const int brw  = iy0 - wlo;
        const int brwc = min(max(brw, 0), WMAXBR);   // 0..38
        badmask |= ((unsigned)brw > (unsigned)WMAXBR) ? (1u << r) : 0u;
        oidx[r] = brwc * W_ + base;
    }

    const bool anybad = __any(badmask != 0u);

    __syncthreads();                   // window 0 staged

    // ---- channel loop: gather -> (rare fixup) -> restage ----
#pragma unroll 1
    for (int ch = 0; ch < CG; ++ch) {
        float* __restrict__ dst = out + bc0 + (size_t)ch * HW_ + spbase;

#pragma unroll
        for (int r = 0; r < BAND; ++r) {
            const int o = oidx[r];
            const float a  = win[o];
            const float bb = win[o + 1];
            const float cl = win[o + W_];
            const float dl = win[o + W_ + 1];
            const float v = w00[r] * a + w01[r] * bb + w10[r] * cl + w11[r] * dl;
            __builtin_nontemporal_store(v, dst + r * W_);
        }

        if (anybad) {
            const float* __restrict__ src = frame + bc0 + (size_t)ch * HW_;
#pragma unroll 1
            for (int r = 0; r < BAND; ++r) {
                if ((badmask >> r) & 1u) {
                    const int py = r0 + r;
                    const float fxr = flx[spbase + r * W_];   // L2 hit
                    const float fyr = fly[spbase + r * W_];

                    const float ix = (float)px + 0.5f * fxr;
                    const float iy = (float)py + 0.5f * fyr;

                    const float ix0f = floorf(ix);
                    const float iy0f = floorf(iy);
                    const float wx1 = ix - ix0f;
                    const float wx0 = 1.0f - wx1;
                    const float wy1 = iy - iy0f;
                    const float wy0 = 1.0f - wy1;

                    const int ix0 = (int)ix0f;
                    const int iy0 = (int)iy0f;

                    const float wx0v = ((unsigned)ix0       < (unsigned)W_) ? wx0 : 0.0f;
                    const float wx1v = ((unsigned)(ix0 + 1) < (unsigned)W_) ? wx1 : 0.0f;
                    const float wy0v = ((unsigned)iy0       < (unsigned)H_) ? wy0 : 0.0f;
                    const float wy1v = ((unsigned)(iy0 + 1) < (unsigned)H_) ? wy1 : 0.0f;

                    const int xc0 = min(max(ix0, 0), W_ - 1);
                    const int xc1 = min(max(ix0 + 1, 0), W_ - 1);
                    const int yc0 = min(max(iy0, 0), H_ - 1);
                    const int yc1 = min(max(iy0 + 1, 0), H_ - 1);

                    const float t00 = src[yc0 * W_ + xc0];
                    const float t01 = src[yc0 * W_ + xc1];
                    const float t10 = src[yc1 * W_ + xc0];
                    const float t11 = src[yc1 * W_ + xc1];

                    const float h0 = wx0v * t00 + wx1v * t01;
                    const float h1 = wx0v * t10 + wx1v * t11;
                    const float v  = wy0v * h0 + wy1v * h1;

                    __builtin_nontemporal_store(v, dst + r * W_);
                }
            }
        }

        if (ch + 1 < CG) {
            __syncthreads();           // all window reads done
            stage(ch + 1);
            __syncthreads();           // new window staged
        }
    }
}

extern "C" void kernel_launch(void* const* d_in, const int* in_sizes, int n_in,
                              void* d_out, int out_size, void* d_ws, size_t ws_size,
                              hipStream_t stream) {
    const float* frame = (const float*)d_in[0];
    const float* flow  = (const float*)d_in[1];
    float* out = (float*)d_out;

    dim3 grid(B_ * NBAND * (C_ / CG));  // 1024 blocks = exactly 4/CU
    dim3 block(256);
    warp_bilinear_kernel<<<grid, block, 0, stream>>>(frame, flow, out);
}